// Round 14
// baseline (2500.326 us; speedup 1.0000x reference)
//
#include <hip/hip_runtime.h>

typedef unsigned long long u64;
typedef unsigned int u32;
typedef unsigned short u16;
typedef float v2f __attribute__((ext_vector_type(2)));

#define NB   8
#define NPC  8192
#define SS   2048
#define KK   32
#define CIN  64
#define NQ   (NB*SS)              // 16384
#define POS_OUT_OFF   (NQ*128)
#define BATCH_OUT_OFF (NQ*128 + NQ*3)
#define INF64 0x7ff0000000000000ULL

// Packed f32 ops via inline asm: IEEE round-to-nearest-even per half,
// bit-identical to the scalar op sequence; immune to -ffp-contract fusing.
// NOTE: gfx950 has NO v_pk_max_f32 (R13 compile fail) — only add/mul/fma.
__device__ __forceinline__ v2f pk_add(v2f a, v2f b) {
    v2f r; asm("v_pk_add_f32 %0, %1, %2" : "=v"(r) : "v"(a), "v"(b)); return r;
}
__device__ __forceinline__ v2f pk_mul(v2f a, v2f b) {
    v2f r; asm("v_pk_mul_f32 %0, %1, %2" : "=v"(r) : "v"(a), "v"(b)); return r;
}
__device__ __forceinline__ v2f pk_fma(v2f a, v2f b, v2f c) {
    v2f r; asm("v_pk_fma_f32 %0, %1, %2, %3" : "=v"(r) : "v"(a), "v"(b), "v"(c)); return r;
}
// scalar max per half (2x v_max_f32): same per-channel semantics as packed
__device__ __forceinline__ v2f pair_max(v2f a, v2f b) {
    return (v2f){fmaxf(a.x, b.x), fmaxf(a.y, b.y)};
}
// key = (mind_bits<<32) | ~idx, viewed as f64. mind_bits <= 0x7f800000 so the
// f64 exponent field < 2047: never NaN -> fmax == exact u64 max (positive).
__device__ __forceinline__ double mkkey(float m, u32 ni) {
    return __hiloint2double((int)__float_as_uint(m), (int)ni);
}
// 64-bit wave max/min via paired 32-bit DPP (gfx9 row_shr/row_bcast sequence).
__device__ __forceinline__ double dpp_wave_max_key(double v) {
#define DPP_LVL(ctrl) { \
    int lo = __double2loint(v), hi = __double2hiint(v); \
    int tlo = __builtin_amdgcn_update_dpp(lo, lo, ctrl, 0xf, 0xf, false); \
    int thi = __builtin_amdgcn_update_dpp(hi, hi, ctrl, 0xf, 0xf, false); \
    v = fmax(v, __hiloint2double(thi, tlo)); }
    DPP_LVL(0x111) DPP_LVL(0x112) DPP_LVL(0x114) DPP_LVL(0x118)
    DPP_LVL(0x142) DPP_LVL(0x143)
#undef DPP_LVL
    return v;                       // valid in lane 63
}
__device__ __forceinline__ double dpp_wave_min_key(double v) {
#define DPP_LVL(ctrl) { \
    int lo = __double2loint(v), hi = __double2hiint(v); \
    int tlo = __builtin_amdgcn_update_dpp(lo, lo, ctrl, 0xf, 0xf, false); \
    int thi = __builtin_amdgcn_update_dpp(hi, hi, ctrl, 0xf, 0xf, false); \
    v = fmin(v, __hiloint2double(thi, tlo)); }
    DPP_LVL(0x111) DPP_LVL(0x112) DPP_LVL(0x114) DPP_LVL(0x118)
    DPP_LVL(0x142) DPP_LVL(0x143)
#undef DPP_LVL
    return v;                       // valid in lane 63
}

// ---------------- Kernel 1: exact farthest point sampling (R6 verbatim) -----
// One block/cloud, 256 thr (4 waves = 1/SIMD) x 32 pts. Single barrier/step:
// per-thread f64-key fold -> paired-DPP wave max -> 4 LDS partials -> combine.
// Measured best: 1604 us (R6). R9/R11/R12 variants all equal-or-worse.
__global__ __launch_bounds__(256) void fps_kernel(const float* __restrict__ pos,
                                                  float* __restrict__ out)
{
    __shared__ float lp[NPC*3];
    __shared__ double red[2][4];
    __shared__ unsigned short hist[SS];
    const int tid  = threadIdx.x;
    const int wid  = tid >> 6;
    const int lane = tid & 63;
    const int cloud = blockIdx.x;
    const float* cp = pos + (size_t)cloud * (NPC*3);

    {   // stage cloud positions into LDS (coalesced float4)
        const float4* s4 = (const float4*)cp;
        float4* d4 = (float4*)lp;
        #pragma unroll
        for (int i = 0; i < 24; ++i) d4[tid + i*256] = s4[tid + i*256];
    }
    __syncthreads();

    v2f px[16], py[16], pz[16], mind[16];
    u32 inv[32];
    const float finf = __int_as_float(0x7f800000);
    #pragma unroll
    for (int k = 0; k < 16; ++k) {
        int j = tid*32 + 2*k;
        px[k] = (v2f){lp[j*3+0], lp[j*3+3]};
        py[k] = (v2f){lp[j*3+1], lp[j*3+4]};
        pz[k] = (v2f){lp[j*3+2], lp[j*3+5]};
        mind[k] = (v2f){finf, finf};
    }
    #pragma unroll
    for (int k = 0; k < 32; ++k) inv[k] = ~(u32)(tid*32 + k);

    float cx = lp[0], cy = lp[1], cz = lp[2];
    u32 widx = 0;

    for (int s = 0; s < SS; ++s) {
        if (tid == 0) hist[s] = (unsigned short)widx;
        // p + (-c) rounds identically to p - c (exact sign flip on c)
        v2f ncx = (v2f){-cx,-cx}, ncy = (v2f){-cy,-cy}, ncz = (v2f){-cz,-cz};
        double kd[8];
        #pragma unroll
        for (int k = 0; k < 16; ++k) {
            v2f dx = pk_add(px[k], ncx);
            v2f dy = pk_add(py[k], ncy);
            v2f dz = pk_add(pz[k], ncz);
            v2f d  = pk_add(pk_add(pk_mul(dx,dx), pk_mul(dy,dy)), pk_mul(dz,dz));
            float m0 = fminf(mind[k].x, d.x);
            float m1 = fminf(mind[k].y, d.y);
            mind[k].x = m0; mind[k].y = m1;
            double ab = fmax(mkkey(m0, inv[2*k]), mkkey(m1, inv[2*k+1]));
            kd[k & 7] = (k < 8) ? ab : fmax(kd[k & 7], ab);
        }
        #pragma unroll
        for (int st = 4; st >= 1; st >>= 1) {
            #pragma unroll
            for (int k = 0; k < st; ++k) kd[k] = fmax(kd[k], kd[k+st]);
        }
        double wk = dpp_wave_max_key(kd[0]);
        if (lane == 63) red[s&1][wid] = wk;
        __syncthreads();                          // single barrier per step
        const double* rb = red[s&1];
        double g = fmax(fmax(rb[0], rb[1]), fmax(rb[2], rb[3]));
        widx = ~(u32)__double2loint(g);
        cx = lp[widx*3+0]; cy = lp[widx*3+1]; cz = lp[widx*3+2];
    }
    __syncthreads();

    float* qout = out + POS_OUT_OFF   + (size_t)cloud * SS * 3;
    float* bout = out + BATCH_OUT_OFF + (size_t)cloud * SS;
    for (int s = tid; s < SS; s += 256) {
        u32 w = hist[s];
        qout[s*3+0] = lp[w*3+0];
        qout[s*3+1] = lp[w*3+1];
        qout[s*3+2] = lp[w*3+2];
        bout[s] = (float)cloud;
    }
}

// ---------------- Kernel 2: radius / 32 smallest-d2 selection ---------------
// Global-direct scan; ballot-compacted candidates in LDS; extraction via
// dynamic-depth register fold (nt=ceil(m/64) instead of fixed 10) + paired-
// DPP f64 wave-min (replaces 12 bpermutes/round with 12 DPP movs + 6 fmin).
// Keys finite-positive (d2<1) or +inf -> v_min_f64 == exact u64 min; unique
// low-word idx -> eliminate-by-equality is safe.
#define CAND_MAX 640
__global__ __launch_bounds__(256) void radius_kernel(const float* __restrict__ pos,
                                                     const float* __restrict__ out,
                                                     int* __restrict__ nidx,
                                                     int* __restrict__ ncnt)
{
    __shared__ u64 cand[4][CAND_MAX];
    const int tid  = threadIdx.x;
    const int wid  = tid >> 6;
    const int lane = tid & 63;
    const float R2 = (float)(0.2 * 0.2);        // float32(0.04) = 0x3D23D70A
    const float* qpos = out + POS_OUT_OFF;
    u64* cw = cand[wid];

    for (int qq = 0; qq < 4; ++qq) {
        const int q     = blockIdx.x*16 + wid*4 + qq;
        const int cloud = q >> 11;
        const float* cp = pos + (size_t)cloud * (NPC*3);
        float qx = qpos[q*3+0], qy = qpos[q*3+1], qz = qpos[q*3+2];

        int m = 0;
        for (int c = 0; c < NPC/64; ++c) {
            int j = c*64 + lane;
            float dx = __fsub_rn(cp[j*3+0], qx);
            float dy = __fsub_rn(cp[j*3+1], qy);
            float dz = __fsub_rn(cp[j*3+2], qz);
            float d2 = __fadd_rn(__fadd_rn(__fmul_rn(dx,dx), __fmul_rn(dy,dy)), __fmul_rn(dz,dz));
            bool in = (d2 <= R2);
            u64 mk = __ballot(in);
            if (in) {
                int p = m + __popcll(mk & ((1ull << lane) - 1ull));
                if (p < CAND_MAX) cw[p] = ((u64)__float_as_uint(d2) << 32) | (u32)j;
            }
            m += __popcll(mk);
        }
        if (m > CAND_MAX) m = CAND_MAX;
        const int nt = (m + 63) >> 6;            // wave-uniform live register count

        double kk[10];
        #pragma unroll
        for (int t = 0; t < 10; ++t) {
            int p = t*64 + lane;
            kk[t] = (p < m) ? __longlong_as_double((long long)cw[p])
                            : __longlong_as_double((long long)INF64);
        }
        int cq = (m < KK) ? m : KK;
        int* nq = nidx + (size_t)q * KK;
        int j0 = 0;
        #pragma unroll 1
        for (int r = 0; r < KK; ++r) {
            double lmin = kk[0];
            #pragma unroll 1
            for (int t = 1; t < nt; ++t) lmin = fmin(lmin, kk[t]);
            lmin = dpp_wave_min_key(lmin);
            u32 lo = (u32)__builtin_amdgcn_readlane(__double2loint(lmin), 63);
            u32 hi = (u32)__builtin_amdgcn_readlane(__double2hiint(lmin), 63);
            int j = (int)lo;
            if (r == 0) j0 = j;                 // center itself (d2=0) is first
            bool isinf = (((u64)hi << 32) | lo) == INF64;
            if (lane == 0) nq[r] = isinf ? j0 : j;
            double lb = __hiloint2double((int)hi, (int)lo);
            #pragma unroll 1
            for (int t = 0; t < nt; ++t)
                if (kk[t] == lb)
                    kk[t] = __longlong_as_double((long long)INF64);
        }
        if (lane == 0) ncnt[q] = cq;
    }
}

// ---------------- Kernel 3: gather + 3-layer MLP + masked max ---------------
// v_pk_fma_f32 on output-channel pairs: halves VALU issue in the dominant FMA
// loops, bit-identical per channel (same fma sequence, same order). relu and
// slot-max as scalar v_max_f32 pairs (no pk_max on gfx950). Weights/biases
// read from global with wave-uniform indices -> s_load broadcasts.
__global__ __launch_bounds__(256) void mlp_kernel(const float* __restrict__ x,
                                                  const float* __restrict__ pos,
                                                  const float* __restrict__ W1, const float* __restrict__ b1,
                                                  const float* __restrict__ W2, const float* __restrict__ b2,
                                                  const float* __restrict__ W3, const float* __restrict__ b3,
                                                  const int* __restrict__ nidx, const int* __restrict__ ncnt,
                                                  float* __restrict__ out)
{
    __shared__ float flds[256*69];

    const int tid   = threadIdx.x;
    const int q     = blockIdx.x * 8 + (tid >> 5);
    const int slot  = tid & 31;
    const int cloud = q >> 11;
    const int j     = nidx[q*KK + slot];
    const bool valid = slot < ncnt[q];
    const size_t row = (size_t)cloud * NPC + (size_t)j;

    const float* qp = out + POS_OUT_OFF + (size_t)q*3;
    float qx = qp[0], qy = qp[1], qz = qp[2];

    float* myf = &flds[tid*69];
    {
        const float4* xr = (const float4*)(x + row*CIN);
        #pragma unroll
        for (int i = 0; i < 16; ++i) {
            float4 v = xr[i];
            myf[i*4+0]=v.x; myf[i*4+1]=v.y; myf[i*4+2]=v.z; myf[i*4+3]=v.w;
        }
        myf[64] = __fsub_rn(pos[row*3+0], qx);
        myf[65] = __fsub_rn(pos[row*3+1], qy);
        myf[66] = __fsub_rn(pos[row*3+2], qz);
    }
    // each thread reads only its own flds region: no barrier needed

    v2f acc[32];
    // ----- layer 1: 67 -> 64, relu -----
    #pragma unroll
    for (int o = 0; o < 32; ++o) acc[o] = ((const v2f*)b1)[o];
    #pragma unroll 2
    for (int i = 0; i < 67; ++i) {
        float fs = myf[i];
        v2f f2 = (v2f){fs, fs};
        const v2f* wr = (const v2f*)(W1 + i*64);
        #pragma unroll
        for (int o = 0; o < 32; ++o) acc[o] = pk_fma(f2, wr[o], acc[o]);
    }
    #pragma unroll
    for (int o = 0; o < 32; ++o) {
        myf[2*o]   = fmaxf(acc[o].x, 0.0f);
        myf[2*o+1] = fmaxf(acc[o].y, 0.0f);
    }

    // ----- layer 2: 64 -> 64, relu -----
    #pragma unroll
    for (int o = 0; o < 32; ++o) acc[o] = ((const v2f*)b2)[o];
    #pragma unroll 2
    for (int i = 0; i < 64; ++i) {
        float fs = myf[i];
        v2f f2 = (v2f){fs, fs};
        const v2f* wr = (const v2f*)(W2 + i*64);
        #pragma unroll
        for (int o = 0; o < 32; ++o) acc[o] = pk_fma(f2, wr[o], acc[o]);
    }
    #pragma unroll
    for (int o = 0; o < 32; ++o) {
        myf[2*o]   = fmaxf(acc[o].x, 0.0f);
        myf[2*o+1] = fmaxf(acc[o].y, 0.0f);
    }

    // ----- layer 3: 64 -> 128 (two 64-wide halves), mask, max over 32 slots --
    float* orow = out + (size_t)q*128;
    const float NEGINF = __int_as_float(0xff800000);
    for (int h = 0; h < 2; ++h) {
        #pragma unroll
        for (int o = 0; o < 32; ++o) acc[o] = ((const v2f*)(b3 + h*64))[o];
        const float* w3h = W3 + h*64;
        #pragma unroll 2
        for (int i = 0; i < 64; ++i) {
            float fs = myf[i];
            v2f f2 = (v2f){fs, fs};
            const v2f* wr = (const v2f*)(w3h + i*128);
            #pragma unroll
            for (int o = 0; o < 32; ++o) acc[o] = pk_fma(f2, wr[o], acc[o]);
        }
        if (!valid) {
            #pragma unroll
            for (int o = 0; o < 32; ++o) acc[o] = (v2f){NEGINF, NEGINF};
        }
        // max over the 32 slots: 64-bit shuffle + 2 scalar max per pair
        #pragma unroll
        for (int off = 16; off >= 1; off >>= 1) {
            #pragma unroll
            for (int o = 0; o < 32; ++o) {
                double d = __shfl_xor(__builtin_bit_cast(double, acc[o]), off);
                acc[o] = pair_max(acc[o], __builtin_bit_cast(v2f, d));
            }
        }
        if (slot == 0) {
            #pragma unroll
            for (int o = 0; o < 16; ++o) {
                float4 v = make_float4(acc[2*o].x, acc[2*o].y, acc[2*o+1].x, acc[2*o+1].y);
                *(float4*)&orow[h*64 + o*4] = v;
            }
        }
    }
}

// ------------------------------- launcher -----------------------------------
extern "C" void kernel_launch(void* const* d_in, const int* in_sizes, int n_in,
                              void* d_out, int out_size, void* d_ws, size_t ws_size,
                              hipStream_t stream) {
    const float* x   = (const float*)d_in[0];
    const float* pos = (const float*)d_in[1];
    // d_in[2]=batch (implicit), d_in[3]=num_samples (K=32 hardcoded)
    const float* W1 = (const float*)d_in[4];
    const float* b1 = (const float*)d_in[5];
    const float* W2 = (const float*)d_in[6];
    const float* b2 = (const float*)d_in[7];
    const float* W3 = (const float*)d_in[8];
    const float* b3 = (const float*)d_in[9];
    float* out = (float*)d_out;

    int* nidx = (int*)d_ws;                  // NQ*KK ints (2 MiB)
    int* ncnt = nidx + (size_t)NQ*KK;        // NQ ints

    hipLaunchKernelGGL(fps_kernel,    dim3(NB),      dim3(256), 0, stream, pos, out);
    hipLaunchKernelGGL(radius_kernel, dim3(NQ/16),   dim3(256), 0, stream, pos, out, nidx, ncnt);
    hipLaunchKernelGGL(mlp_kernel,    dim3(NQ/8),    dim3(256), 0, stream,
                       x, pos, W1, b1, W2, b2, W3, b3, nidx, ncnt, out);
}

// Round 15
// 2341.004 us; speedup vs baseline: 1.0681x; 1.0681x over previous
//
#include <hip/hip_runtime.h>

typedef unsigned long long u64;
typedef unsigned int u32;
typedef unsigned short u16;
typedef float v2f __attribute__((ext_vector_type(2)));

#define NB   8
#define NPC  8192
#define SS   2048
#define KK   32
#define CIN  64
#define NQ   (NB*SS)              // 16384
#define POS_OUT_OFF   (NQ*128)
#define BATCH_OUT_OFF (NQ*128 + NQ*3)
#define INF64 0x7ff0000000000000ULL

// Packed f32 ops via inline asm: IEEE round-to-nearest-even per half,
// bit-identical to the scalar op sequence; immune to -ffp-contract fusing.
// NOTE: gfx950 has NO v_pk_max_f32 (R13 compile fail) — only add/mul/fma.
__device__ __forceinline__ v2f pk_add(v2f a, v2f b) {
    v2f r; asm("v_pk_add_f32 %0, %1, %2" : "=v"(r) : "v"(a), "v"(b)); return r;
}
__device__ __forceinline__ v2f pk_mul(v2f a, v2f b) {
    v2f r; asm("v_pk_mul_f32 %0, %1, %2" : "=v"(r) : "v"(a), "v"(b)); return r;
}
__device__ __forceinline__ v2f pk_fma(v2f a, v2f b, v2f c) {
    v2f r; asm("v_pk_fma_f32 %0, %1, %2, %3" : "=v"(r) : "v"(a), "v"(b), "v"(c)); return r;
}
// scalar max per half (2x v_max_f32): same per-channel semantics as packed
__device__ __forceinline__ v2f pair_max(v2f a, v2f b) {
    return (v2f){fmaxf(a.x, b.x), fmaxf(a.y, b.y)};
}
// key = (mind_bits<<32) | ~idx, viewed as f64. mind_bits <= 0x7f800000 so the
// f64 exponent field < 2047: never NaN -> fmax == exact u64 max (positive).
__device__ __forceinline__ double mkkey(float m, u32 ni) {
    return __hiloint2double((int)__float_as_uint(m), (int)ni);
}
// 64-bit wave max via paired 32-bit DPP (gfx9 row_shr/row_bcast sequence).
__device__ __forceinline__ double dpp_wave_max_key(double v) {
#define DPP_LVL(ctrl) { \
    int lo = __double2loint(v), hi = __double2hiint(v); \
    int tlo = __builtin_amdgcn_update_dpp(lo, lo, ctrl, 0xf, 0xf, false); \
    int thi = __builtin_amdgcn_update_dpp(hi, hi, ctrl, 0xf, 0xf, false); \
    v = fmax(v, __hiloint2double(thi, tlo)); }
    DPP_LVL(0x111) DPP_LVL(0x112) DPP_LVL(0x114) DPP_LVL(0x118)
    DPP_LVL(0x142) DPP_LVL(0x143)
#undef DPP_LVL
    return v;                       // valid in lane 63
}

// ---------------- Kernel 1: exact farthest point sampling (R6 verbatim) -----
// One block/cloud, 256 thr (4 waves = 1/SIMD) x 32 pts. Single barrier/step:
// per-thread f64-key fold -> paired-DPP wave max -> 4 LDS partials -> combine.
// Measured best: 1604 us (R6/R14). All structural variants equal-or-worse.
__global__ __launch_bounds__(256) void fps_kernel(const float* __restrict__ pos,
                                                  float* __restrict__ out)
{
    __shared__ float lp[NPC*3];
    __shared__ double red[2][4];
    __shared__ unsigned short hist[SS];
    const int tid  = threadIdx.x;
    const int wid  = tid >> 6;
    const int lane = tid & 63;
    const int cloud = blockIdx.x;
    const float* cp = pos + (size_t)cloud * (NPC*3);

    {   // stage cloud positions into LDS (coalesced float4)
        const float4* s4 = (const float4*)cp;
        float4* d4 = (float4*)lp;
        #pragma unroll
        for (int i = 0; i < 24; ++i) d4[tid + i*256] = s4[tid + i*256];
    }
    __syncthreads();

    v2f px[16], py[16], pz[16], mind[16];
    u32 inv[32];
    const float finf = __int_as_float(0x7f800000);
    #pragma unroll
    for (int k = 0; k < 16; ++k) {
        int j = tid*32 + 2*k;
        px[k] = (v2f){lp[j*3+0], lp[j*3+3]};
        py[k] = (v2f){lp[j*3+1], lp[j*3+4]};
        pz[k] = (v2f){lp[j*3+2], lp[j*3+5]};
        mind[k] = (v2f){finf, finf};
    }
    #pragma unroll
    for (int k = 0; k < 32; ++k) inv[k] = ~(u32)(tid*32 + k);

    float cx = lp[0], cy = lp[1], cz = lp[2];
    u32 widx = 0;

    for (int s = 0; s < SS; ++s) {
        if (tid == 0) hist[s] = (unsigned short)widx;
        // p + (-c) rounds identically to p - c (exact sign flip on c)
        v2f ncx = (v2f){-cx,-cx}, ncy = (v2f){-cy,-cy}, ncz = (v2f){-cz,-cz};
        double kd[8];
        #pragma unroll
        for (int k = 0; k < 16; ++k) {
            v2f dx = pk_add(px[k], ncx);
            v2f dy = pk_add(py[k], ncy);
            v2f dz = pk_add(pz[k], ncz);
            v2f d  = pk_add(pk_add(pk_mul(dx,dx), pk_mul(dy,dy)), pk_mul(dz,dz));
            float m0 = fminf(mind[k].x, d.x);
            float m1 = fminf(mind[k].y, d.y);
            mind[k].x = m0; mind[k].y = m1;
            double ab = fmax(mkkey(m0, inv[2*k]), mkkey(m1, inv[2*k+1]));
            kd[k & 7] = (k < 8) ? ab : fmax(kd[k & 7], ab);
        }
        #pragma unroll
        for (int st = 4; st >= 1; st >>= 1) {
            #pragma unroll
            for (int k = 0; k < st; ++k) kd[k] = fmax(kd[k], kd[k+st]);
        }
        double wk = dpp_wave_max_key(kd[0]);
        if (lane == 63) red[s&1][wid] = wk;
        __syncthreads();                          // single barrier per step
        const double* rb = red[s&1];
        double g = fmax(fmax(rb[0], rb[1]), fmax(rb[2], rb[3]));
        widx = ~(u32)__double2loint(g);
        cx = lp[widx*3+0]; cy = lp[widx*3+1]; cz = lp[widx*3+2];
    }
    __syncthreads();

    float* qout = out + POS_OUT_OFF   + (size_t)cloud * SS * 3;
    float* bout = out + BATCH_OUT_OFF + (size_t)cloud * SS;
    for (int s = tid; s < SS; s += 256) {
        u32 w = hist[s];
        qout[s*3+0] = lp[w*3+0];
        qout[s*3+1] = lp[w*3+1];
        qout[s*3+2] = lp[w*3+2];
        bout[s] = (float)cloud;
    }
}

// ---------------- Kernel 2: radius / 32 smallest-d2 (R6 verbatim) -----------
// Global-direct scan, ballot-compacted candidates in LDS, f64-key min
// extraction with STATICALLY-unrolled register fold (kk[10] stays in VGPRs —
// R14's dynamic-depth loop sent it to scratch: ~2.5x radius regression).
#define CAND_MAX 640
__global__ __launch_bounds__(256) void radius_kernel(const float* __restrict__ pos,
                                                     const float* __restrict__ out,
                                                     int* __restrict__ nidx,
                                                     int* __restrict__ ncnt)
{
    __shared__ u64 cand[4][CAND_MAX];
    const int tid  = threadIdx.x;
    const int wid  = tid >> 6;
    const int lane = tid & 63;
    const float R2 = (float)(0.2 * 0.2);        // float32(0.04) = 0x3D23D70A
    const float* qpos = out + POS_OUT_OFF;
    u64* cw = cand[wid];

    for (int qq = 0; qq < 4; ++qq) {
        const int q     = blockIdx.x*16 + wid*4 + qq;
        const int cloud = q >> 11;
        const float* cp = pos + (size_t)cloud * (NPC*3);
        float qx = qpos[q*3+0], qy = qpos[q*3+1], qz = qpos[q*3+2];

        int m = 0;
        for (int c = 0; c < NPC/64; ++c) {
            int j = c*64 + lane;
            float dx = __fsub_rn(cp[j*3+0], qx);
            float dy = __fsub_rn(cp[j*3+1], qy);
            float dz = __fsub_rn(cp[j*3+2], qz);
            float d2 = __fadd_rn(__fadd_rn(__fmul_rn(dx,dx), __fmul_rn(dy,dy)), __fmul_rn(dz,dz));
            bool in = (d2 <= R2);
            u64 mk = __ballot(in);
            if (in) {
                int p = m + __popcll(mk & ((1ull << lane) - 1ull));
                if (p < CAND_MAX) cw[p] = ((u64)__float_as_uint(d2) << 32) | (u32)j;
            }
            m += __popcll(mk);
        }
        if (m > CAND_MAX) m = CAND_MAX;

        double kk[10];
        #pragma unroll
        for (int t = 0; t < 10; ++t) {
            int p = t*64 + lane;
            kk[t] = (p < m) ? __longlong_as_double((long long)cw[p])
                            : __longlong_as_double((long long)INF64);
        }
        int cq = (m < KK) ? m : KK;
        int* nq = nidx + (size_t)q * KK;
        int j0 = 0;
        #pragma unroll 1
        for (int r = 0; r < KK; ++r) {
            double lmin = kk[0];
            #pragma unroll
            for (int t = 1; t < 10; ++t) lmin = fmin(lmin, kk[t]);
            #pragma unroll
            for (int off = 32; off >= 1; off >>= 1)
                lmin = fmin(lmin, __shfl_xor(lmin, off));
            u64 lb = (u64)__double_as_longlong(lmin);
            int j = (int)(u32)lb;
            if (r == 0) j0 = j;                 // center itself (d2=0) is first
            if (lane == 0) nq[r] = (lb == INF64) ? j0 : j;
            #pragma unroll
            for (int t = 0; t < 10; ++t)
                if ((u64)__double_as_longlong(kk[t]) == lb)
                    kk[t] = __longlong_as_double((long long)INF64);
        }
        if (lane == 0) ncnt[q] = cq;
    }
}

// ---------------- Kernel 3: gather + 3-layer MLP + masked max ---------------
// v_pk_fma_f32 on output-channel pairs (halves FMA issue, bit-identical per
// channel) with float4 weight loads preserved (R14's v2f loads doubled VMEM
// issue). dwordx4 dest regs are even-aligned -> both v2f halves are valid
// pairs, no extra movs. relu/slot-max as scalar v_max_f32 (no pk_max on
// gfx950); slot-reduce uses 64-bit shuffles (half the bpermutes).
__global__ __launch_bounds__(256) void mlp_kernel(const float* __restrict__ x,
                                                  const float* __restrict__ pos,
                                                  const float* __restrict__ W1, const float* __restrict__ b1,
                                                  const float* __restrict__ W2, const float* __restrict__ b2,
                                                  const float* __restrict__ W3, const float* __restrict__ b3,
                                                  const int* __restrict__ nidx, const int* __restrict__ ncnt,
                                                  float* __restrict__ out)
{
    __shared__ float flds[256*69];

    const int tid   = threadIdx.x;
    const int q     = blockIdx.x * 8 + (tid >> 5);
    const int slot  = tid & 31;
    const int cloud = q >> 11;
    const int j     = nidx[q*KK + slot];
    const bool valid = slot < ncnt[q];
    const size_t row = (size_t)cloud * NPC + (size_t)j;

    const float* qp = out + POS_OUT_OFF + (size_t)q*3;
    float qx = qp[0], qy = qp[1], qz = qp[2];

    float* myf = &flds[tid*69];
    {
        const float4* xr = (const float4*)(x + row*CIN);
        #pragma unroll
        for (int i = 0; i < 16; ++i) {
            float4 v = xr[i];
            myf[i*4+0]=v.x; myf[i*4+1]=v.y; myf[i*4+2]=v.z; myf[i*4+3]=v.w;
        }
        myf[64] = __fsub_rn(pos[row*3+0], qx);
        myf[65] = __fsub_rn(pos[row*3+1], qy);
        myf[66] = __fsub_rn(pos[row*3+2], qz);
    }
    // each thread reads only its own flds region: no barrier needed

    v2f acc[32];
    // ----- layer 1: 67 -> 64, relu -----
    #pragma unroll
    for (int o = 0; o < 32; ++o) acc[o] = ((const v2f*)b1)[o];
    #pragma unroll 2
    for (int i = 0; i < 67; ++i) {
        float fs = myf[i];
        v2f f2 = (v2f){fs, fs};
        const float4* wr = (const float4*)(W1 + i*64);
        #pragma unroll
        for (int o4 = 0; o4 < 16; ++o4) {
            float4 wv = wr[o4];
            acc[2*o4]   = pk_fma(f2, (v2f){wv.x, wv.y}, acc[2*o4]);
            acc[2*o4+1] = pk_fma(f2, (v2f){wv.z, wv.w}, acc[2*o4+1]);
        }
    }
    #pragma unroll
    for (int o = 0; o < 32; ++o) {
        myf[2*o]   = fmaxf(acc[o].x, 0.0f);
        myf[2*o+1] = fmaxf(acc[o].y, 0.0f);
    }

    // ----- layer 2: 64 -> 64, relu -----
    #pragma unroll
    for (int o = 0; o < 32; ++o) acc[o] = ((const v2f*)b2)[o];
    #pragma unroll 2
    for (int i = 0; i < 64; ++i) {
        float fs = myf[i];
        v2f f2 = (v2f){fs, fs};
        const float4* wr = (const float4*)(W2 + i*64);
        #pragma unroll
        for (int o4 = 0; o4 < 16; ++o4) {
            float4 wv = wr[o4];
            acc[2*o4]   = pk_fma(f2, (v2f){wv.x, wv.y}, acc[2*o4]);
            acc[2*o4+1] = pk_fma(f2, (v2f){wv.z, wv.w}, acc[2*o4+1]);
        }
    }
    #pragma unroll
    for (int o = 0; o < 32; ++o) {
        myf[2*o]   = fmaxf(acc[o].x, 0.0f);
        myf[2*o+1] = fmaxf(acc[o].y, 0.0f);
    }

    // ----- layer 3: 64 -> 128 (two 64-wide halves), mask, max over 32 slots --
    float* orow = out + (size_t)q*128;
    const float NEGINF = __int_as_float(0xff800000);
    for (int h = 0; h < 2; ++h) {
        #pragma unroll
        for (int o = 0; o < 32; ++o) acc[o] = ((const v2f*)(b3 + h*64))[o];
        const float* w3h = W3 + h*64;
        #pragma unroll 2
        for (int i = 0; i < 64; ++i) {
            float fs = myf[i];
            v2f f2 = (v2f){fs, fs};
            const float4* wr = (const float4*)(w3h + i*128);
            #pragma unroll
            for (int o4 = 0; o4 < 16; ++o4) {
                float4 wv = wr[o4];
                acc[2*o4]   = pk_fma(f2, (v2f){wv.x, wv.y}, acc[2*o4]);
                acc[2*o4+1] = pk_fma(f2, (v2f){wv.z, wv.w}, acc[2*o4+1]);
            }
        }
        if (!valid) {
            #pragma unroll
            for (int o = 0; o < 32; ++o) acc[o] = (v2f){NEGINF, NEGINF};
        }
        // max over the 32 slots: 64-bit shuffle + 2 scalar max per pair
        #pragma unroll
        for (int off = 16; off >= 1; off >>= 1) {
            #pragma unroll
            for (int o = 0; o < 32; ++o) {
                double d = __shfl_xor(__builtin_bit_cast(double, acc[o]), off);
                acc[o] = pair_max(acc[o], __builtin_bit_cast(v2f, d));
            }
        }
        if (slot == 0) {
            #pragma unroll
            for (int o = 0; o < 16; ++o) {
                float4 v = make_float4(acc[2*o].x, acc[2*o].y, acc[2*o+1].x, acc[2*o+1].y);
                *(float4*)&orow[h*64 + o*4] = v;
            }
        }
    }
}

// ------------------------------- launcher -----------------------------------
extern "C" void kernel_launch(void* const* d_in, const int* in_sizes, int n_in,
                              void* d_out, int out_size, void* d_ws, size_t ws_size,
                              hipStream_t stream) {
    const float* x   = (const float*)d_in[0];
    const float* pos = (const float*)d_in[1];
    // d_in[2]=batch (implicit), d_in[3]=num_samples (K=32 hardcoded)
    const float* W1 = (const float*)d_in[4];
    const float* b1 = (const float*)d_in[5];
    const float* W2 = (const float*)d_in[6];
    const float* b2 = (const float*)d_in[7];
    const float* W3 = (const float*)d_in[8];
    const float* b3 = (const float*)d_in[9];
    float* out = (float*)d_out;

    int* nidx = (int*)d_ws;                  // NQ*KK ints (2 MiB)
    int* ncnt = nidx + (size_t)NQ*KK;        // NQ ints

    hipLaunchKernelGGL(fps_kernel,    dim3(NB),      dim3(256), 0, stream, pos, out);
    hipLaunchKernelGGL(radius_kernel, dim3(NQ/16),   dim3(256), 0, stream, pos, out, nidx, ncnt);
    hipLaunchKernelGGL(mlp_kernel,    dim3(NQ/8),    dim3(256), 0, stream,
                       x, pos, W1, b1, W2, b2, W3, b3, nidx, ncnt, out);
}